// Round 1
// baseline (656.357 us; speedup 1.0000x reference)
//
#include <hip/hip_runtime.h>

#define NN 100000
#define NE 600000
#define DD 128
#define BN_EPS 1e-5f

// ---------------------------------------------------------------- init
__global__ __launch_bounds__(256) void k_init(float* __restrict__ deg,
                                              float* __restrict__ sums,
                                              float* __restrict__ sumsq) {
    int i = blockIdx.x * 256 + threadIdx.x;
    if (i < NN) deg[i] = 1.0f;          // self-loop contributes 1 to degree
    if (i < DD) { sums[i] = 0.0f; sumsq[i] = 0.0f; }
}

// ---------------------------------------------------------------- degree
__global__ __launch_bounds__(256) void k_degree(const int* __restrict__ dst,
                                                float* __restrict__ deg) {
    int e = blockIdx.x * 256 + threadIdx.x;
    if (e < NE) unsafeAtomicAdd(&deg[dst[e]], 1.0f);
}

// ---------------------------------------------------------------- GEMM h = x@W, fused self-loop + bias
// block: 256 threads, tile 32 rows x 128 cols, 4x4 register blocking
__global__ __launch_bounds__(256) void k_gemm(const float* __restrict__ x,
                                              const float* __restrict__ W,
                                              const float* __restrict__ b,
                                              const float* __restrict__ deg,
                                              float* __restrict__ h,
                                              float* __restrict__ agg,
                                              float* __restrict__ dinv) {
    __shared__ float Ws[DD][DD];   // 64 KiB
    __shared__ float Xs[32][DD];   // 16 KiB
    const int tid  = threadIdx.x;
    const int base = blockIdx.x * 32;

    // W -> LDS (4096 float4 / 256 threads = 16 each), coalesced
    {
        const float4* Wg = (const float4*)W;
        float4*       Wl = (float4*)&Ws[0][0];
        #pragma unroll
        for (int i = 0; i < 16; ++i) Wl[i * 256 + tid] = Wg[i * 256 + tid];
    }
    // x tile -> LDS (1024 float4 / 256 threads = 4 each)
    {
        const float4* Xg = (const float4*)x;
        float4*       Xl = (float4*)&Xs[0][0];
        #pragma unroll
        for (int i = 0; i < 4; ++i) {
            int f  = i * 256 + tid;
            int r  = base + (f >> 5);
            int c4 = f & 31;
            float4 v = make_float4(0.f, 0.f, 0.f, 0.f);
            if (r < NN) v = Xg[(size_t)r * 32 + c4];
            Xl[f] = v;
        }
    }
    __syncthreads();

    const int c0 = (tid & 31) * 4;   // 4 consecutive cols per thread
    const int r0 = (tid >> 5) * 4;   // 4 rows per thread (within tile)

    float acc[4][4];
    #pragma unroll
    for (int i = 0; i < 4; ++i)
        #pragma unroll
        for (int j = 0; j < 4; ++j) acc[i][j] = 0.0f;

    #pragma unroll 4
    for (int k = 0; k < DD; ++k) {
        float4 w = *(const float4*)&Ws[k][c0];   // b128, conflict-free
        #pragma unroll
        for (int i = 0; i < 4; ++i) {
            float a = Xs[r0 + i][k];             // wave-broadcast
            acc[i][0] = fmaf(a, w.x, acc[i][0]);
            acc[i][1] = fmaf(a, w.y, acc[i][1]);
            acc[i][2] = fmaf(a, w.z, acc[i][2]);
            acc[i][3] = fmaf(a, w.w, acc[i][3]);
        }
    }

    float4 bb = *(const float4*)&b[c0];
    #pragma unroll
    for (int i = 0; i < 4; ++i) {
        int r = base + r0 + i;
        if (r < NN) {
            float id = 1.0f / deg[r];            // self-loop norm = dinv^2
            float4 hv = make_float4(acc[i][0], acc[i][1], acc[i][2], acc[i][3]);
            *(float4*)&h[(size_t)r * DD + c0] = hv;
            float4 av = make_float4(bb.x + hv.x * id, bb.y + hv.y * id,
                                    bb.z + hv.z * id, bb.w + hv.w * id);
            *(float4*)&agg[(size_t)r * DD + c0] = av;
        }
    }
    if (tid < 32) {
        int r = base + tid;
        if (r < NN) dinv[r] = rsqrtf(deg[r]);
    }
}

// ---------------------------------------------------------------- edge scatter
// one wave (64 lanes) per edge; float2 per lane covers D=128
__global__ __launch_bounds__(256) void k_scatter(const int* __restrict__ src,
                                                 const int* __restrict__ dst,
                                                 const float* __restrict__ h,
                                                 const float* __restrict__ dinv,
                                                 float* __restrict__ agg) {
    int e = blockIdx.x * 4 + (threadIdx.x >> 6);
    if (e >= NE) return;
    int lane = threadIdx.x & 63;
    int s = src[e], t = dst[e];
    float nrm = dinv[s] * dinv[t];
    float2 v = *(const float2*)&h[(size_t)s * DD + lane * 2];
    unsafeAtomicAdd(&agg[(size_t)t * DD + lane * 2],     v.x * nrm);
    unsafeAtomicAdd(&agg[(size_t)t * DD + lane * 2 + 1], v.y * nrm);
}

// ---------------------------------------------------------------- BN stats (col sums over rows)
__global__ __launch_bounds__(256) void k_stats(const float* __restrict__ agg,
                                               float* __restrict__ sums,
                                               float* __restrict__ sumsq) {
    __shared__ float s1[256], s2[256];
    int col  = threadIdx.x & 127;
    int half = threadIdx.x >> 7;
    float s = 0.0f, ss = 0.0f;
    for (int r = blockIdx.x * 2 + half; r < NN; r += gridDim.x * 2) {
        float v = agg[(size_t)r * DD + col];
        s += v; ss += v * v;
    }
    s1[threadIdx.x] = s; s2[threadIdx.x] = ss;
    __syncthreads();
    if (half == 0) {
        s  += s1[threadIdx.x + 128];
        ss += s2[threadIdx.x + 128];
        unsafeAtomicAdd(&sums[col],  s);
        unsafeAtomicAdd(&sumsq[col], ss);
    }
}

// ---------------------------------------------------------------- BN apply + ReLU + residual
__global__ __launch_bounds__(256) void k_final(float* __restrict__ out,
                                               const float* __restrict__ x,
                                               const float* __restrict__ gamma,
                                               const float* __restrict__ beta,
                                               const float* __restrict__ sums,
                                               const float* __restrict__ sumsq) {
    int idx = blockIdx.x * 256 + threadIdx.x;       // float4 index
    if (idx >= NN * DD / 4) return;
    int c4 = idx & 31;                               // float4 col index

    const float invN = 1.0f / (float)NN;
    float4 sm  = ((const float4*)sums)[c4];
    float4 sq  = ((const float4*)sumsq)[c4];
    float4 g   = ((const float4*)gamma)[c4];
    float4 be  = ((const float4*)beta)[c4];
    float4 v   = ((float4*)out)[idx];
    float4 xr  = ((const float4*)x)[idx];

    float m0 = sm.x * invN, m1 = sm.y * invN, m2 = sm.z * invN, m3 = sm.w * invN;
    float r0 = rsqrtf(sq.x * invN - m0 * m0 + BN_EPS);
    float r1 = rsqrtf(sq.y * invN - m1 * m1 + BN_EPS);
    float r2 = rsqrtf(sq.z * invN - m2 * m2 + BN_EPS);
    float r3 = rsqrtf(sq.w * invN - m3 * m3 + BN_EPS);

    float4 o;
    o.x = fmaxf((v.x - m0) * r0 * g.x + be.x, 0.0f) + xr.x;
    o.y = fmaxf((v.y - m1) * r1 * g.y + be.y, 0.0f) + xr.y;
    o.z = fmaxf((v.z - m2) * r2 * g.z + be.z, 0.0f) + xr.z;
    o.w = fmaxf((v.w - m3) * r3 * g.w + be.w, 0.0f) + xr.w;
    ((float4*)out)[idx] = o;
}

// ---------------------------------------------------------------- launch
extern "C" void kernel_launch(void* const* d_in, const int* in_sizes, int n_in,
                              void* d_out, int out_size, void* d_ws, size_t ws_size,
                              hipStream_t stream) {
    const float* x     = (const float*)d_in[0];
    const int*   ei    = (const int*)d_in[1];    // [2, NE]
    const float* W     = (const float*)d_in[2];
    const float* b     = (const float*)d_in[3];
    const float* gamma = (const float*)d_in[4];
    const float* beta  = (const float*)d_in[5];
    float*       out   = (float*)d_out;

    float* ws    = (float*)d_ws;
    float* h     = ws;                          // NN*DD floats (51.2 MB)
    float* deg   = h + (size_t)NN * DD;         // NN
    float* dinv  = deg + NN;                    // NN
    float* sums  = dinv + NN;                   // DD
    float* sumsq = sums + DD;                   // DD

    const int* src = ei;        // edge_index[0]
    const int* dst = ei + NE;   // edge_index[1]

    k_init   <<<(NN + 255) / 256, 256, 0, stream>>>(deg, sums, sumsq);
    k_degree <<<(NE + 255) / 256, 256, 0, stream>>>(dst, deg);
    k_gemm   <<<(NN + 31) / 32,   256, 0, stream>>>(x, W, b, deg, h, out, dinv);
    k_scatter<<<(NE + 3) / 4,     256, 0, stream>>>(src, dst, h, dinv, out);
    k_stats  <<<1024,             256, 0, stream>>>(out, sums, sumsq);
    k_final  <<<(NN * DD / 4 + 255) / 256, 256, 0, stream>>>(out, x, gamma, beta, sums, sumsq);
}

// Round 2
// 270.522 us; speedup vs baseline: 2.4263x; 2.4263x over previous
//
#include <hip/hip_runtime.h>

#define NN 100000
#define NE 600000
#define DD 128
#define BN_EPS 1e-5f
#define NB1 391   // (NN+255)/256 scan blocks

// ---------------------------------------------------------------- init
__global__ __launch_bounds__(256) void k_init(int* __restrict__ cnt,
                                              float* __restrict__ sums,
                                              float* __restrict__ sumsq) {
    int i = blockIdx.x * 256 + threadIdx.x;
    if (i < NN) cnt[i] = 0;
    if (i < DD) { sums[i] = 0.0f; sumsq[i] = 0.0f; }
}

// ---------------------------------------------------------------- count incoming edges
__global__ __launch_bounds__(256) void k_count(const int* __restrict__ dst,
                                               int* __restrict__ cnt) {
    int e = blockIdx.x * 256 + threadIdx.x;
    if (e < NE) atomicAdd(&cnt[dst[e]], 1);
}

// ---------------------------------------------------------------- scan pass 1: per-block exclusive scan
__global__ __launch_bounds__(256) void k_scan1(const int* __restrict__ cnt,
                                               int* __restrict__ offs,
                                               int* __restrict__ bsum) {
    __shared__ int tmp[256];
    int tid = threadIdx.x;
    int i = blockIdx.x * 256 + tid;
    int v = (i < NN) ? cnt[i] : 0;
    tmp[tid] = v;
    __syncthreads();
    #pragma unroll
    for (int d = 1; d < 256; d <<= 1) {
        int t = (tid >= d) ? tmp[tid - d] : 0;
        __syncthreads();
        tmp[tid] += t;
        __syncthreads();
    }
    if (i < NN) offs[i] = tmp[tid] - v;          // exclusive
    if (tid == 255) bsum[blockIdx.x] = tmp[255]; // block total
}

// ---------------------------------------------------------------- scan pass 2: scan the block sums (1 block)
__global__ __launch_bounds__(512) void k_scan2(int* __restrict__ bsum) {
    __shared__ int tmp[512];
    int tid = threadIdx.x;
    int v = (tid < NB1) ? bsum[tid] : 0;
    tmp[tid] = v;
    __syncthreads();
    #pragma unroll
    for (int d = 1; d < 512; d <<= 1) {
        int t = (tid >= d) ? tmp[tid - d] : 0;
        __syncthreads();
        tmp[tid] += t;
        __syncthreads();
    }
    if (tid < NB1) bsum[tid] = tmp[tid] - v;     // exclusive
}

// ---------------------------------------------------------------- scan pass 3: add block offset, init cursor, dinv
__global__ __launch_bounds__(256) void k_scan3(int* __restrict__ offs,
                                               const int* __restrict__ bsum,
                                               const int* __restrict__ cnt,
                                               int* __restrict__ cur,
                                               float* __restrict__ dinv) {
    int i = blockIdx.x * 256 + threadIdx.x;
    if (i < NN) {
        int o = offs[i] + bsum[blockIdx.x];
        offs[i] = o;
        cur[i]  = o;
        dinv[i] = rsqrtf((float)(cnt[i] + 1));   // +1 self-loop
    }
}

// ---------------------------------------------------------------- fill CSR buckets with src ids
__global__ __launch_bounds__(256) void k_fill(const int* __restrict__ src,
                                              const int* __restrict__ dst,
                                              int* __restrict__ cur,
                                              int* __restrict__ srcs) {
    int e = blockIdx.x * 256 + threadIdx.x;
    if (e < NE) {
        int t = dst[e];
        int slot = atomicAdd(&cur[t], 1);
        srcs[slot] = src[e];
    }
}

// ---------------------------------------------------------------- GEMM h = x@W
// block: 256 threads, tile 32 rows x 128 cols, 4x4 register blocking
__global__ __launch_bounds__(256) void k_gemm(const float* __restrict__ x,
                                              const float* __restrict__ W,
                                              float* __restrict__ h) {
    __shared__ float Ws[DD][DD];   // 64 KiB
    __shared__ float Xs[32][DD];   // 16 KiB
    const int tid  = threadIdx.x;
    const int base = blockIdx.x * 32;

    {
        const float4* Wg = (const float4*)W;
        float4*       Wl = (float4*)&Ws[0][0];
        #pragma unroll
        for (int i = 0; i < 16; ++i) Wl[i * 256 + tid] = Wg[i * 256 + tid];
    }
    {
        const float4* Xg = (const float4*)x;
        float4*       Xl = (float4*)&Xs[0][0];
        #pragma unroll
        for (int i = 0; i < 4; ++i) {
            int f  = i * 256 + tid;
            int r  = base + (f >> 5);
            int c4 = f & 31;
            float4 v = make_float4(0.f, 0.f, 0.f, 0.f);
            if (r < NN) v = Xg[(size_t)r * 32 + c4];
            Xl[f] = v;
        }
    }
    __syncthreads();

    const int c0 = (tid & 31) * 4;
    const int r0 = (tid >> 5) * 4;

    float acc[4][4];
    #pragma unroll
    for (int i = 0; i < 4; ++i)
        #pragma unroll
        for (int j = 0; j < 4; ++j) acc[i][j] = 0.0f;

    #pragma unroll 4
    for (int k = 0; k < DD; ++k) {
        float4 w = *(const float4*)&Ws[k][c0];
        #pragma unroll
        for (int i = 0; i < 4; ++i) {
            float a = Xs[r0 + i][k];
            acc[i][0] = fmaf(a, w.x, acc[i][0]);
            acc[i][1] = fmaf(a, w.y, acc[i][1]);
            acc[i][2] = fmaf(a, w.z, acc[i][2]);
            acc[i][3] = fmaf(a, w.w, acc[i][3]);
        }
    }

    #pragma unroll
    for (int i = 0; i < 4; ++i) {
        int r = base + r0 + i;
        if (r < NN)
            *(float4*)&h[(size_t)r * DD + c0] =
                make_float4(acc[i][0], acc[i][1], acc[i][2], acc[i][3]);
    }
}

// ---------------------------------------------------------------- gather: one wave per node, no atomics
__global__ __launch_bounds__(256) void k_gather(const int* __restrict__ offs,
                                                const int* __restrict__ cnt,
                                                const int* __restrict__ srcs,
                                                const float* __restrict__ h,
                                                const float* __restrict__ dinv,
                                                const float* __restrict__ b,
                                                float* __restrict__ out) {
    int i = blockIdx.x * 4 + (threadIdx.x >> 6);
    if (i >= NN) return;
    int lane = threadIdx.x & 63;

    const float2* h2 = (const float2*)h;
    float di = dinv[i];
    float2 acc = h2[(size_t)i * 64 + lane];      // self-loop term
    float sn = di * di;
    acc.x *= sn; acc.y *= sn;

    int beg = offs[i];
    int n   = cnt[i];
    for (int k = 0; k < n; ++k) {
        int s = srcs[beg + k];
        float nr = dinv[s] * di;
        float2 v = h2[(size_t)s * 64 + lane];
        acc.x = fmaf(v.x, nr, acc.x);
        acc.y = fmaf(v.y, nr, acc.y);
    }
    float2 bb = ((const float2*)b)[lane];
    acc.x += bb.x; acc.y += bb.y;
    ((float2*)out)[(size_t)i * 64 + lane] = acc;
}

// ---------------------------------------------------------------- BN stats (col sums over rows)
__global__ __launch_bounds__(256) void k_stats(const float* __restrict__ agg,
                                               float* __restrict__ sums,
                                               float* __restrict__ sumsq) {
    __shared__ float s1[256], s2[256];
    int col  = threadIdx.x & 127;
    int half = threadIdx.x >> 7;
    float s = 0.0f, ss = 0.0f;
    for (int r = blockIdx.x * 2 + half; r < NN; r += gridDim.x * 2) {
        float v = agg[(size_t)r * DD + col];
        s += v; ss += v * v;
    }
    s1[threadIdx.x] = s; s2[threadIdx.x] = ss;
    __syncthreads();
    if (half == 0) {
        s  += s1[threadIdx.x + 128];
        ss += s2[threadIdx.x + 128];
        unsafeAtomicAdd(&sums[col],  s);
        unsafeAtomicAdd(&sumsq[col], ss);
    }
}

// ---------------------------------------------------------------- BN apply + ReLU + residual
__global__ __launch_bounds__(256) void k_final(float* __restrict__ out,
                                               const float* __restrict__ x,
                                               const float* __restrict__ gamma,
                                               const float* __restrict__ beta,
                                               const float* __restrict__ sums,
                                               const float* __restrict__ sumsq) {
    int idx = blockIdx.x * 256 + threadIdx.x;
    if (idx >= NN * DD / 4) return;
    int c4 = idx & 31;

    const float invN = 1.0f / (float)NN;
    float4 sm  = ((const float4*)sums)[c4];
    float4 sq  = ((const float4*)sumsq)[c4];
    float4 g   = ((const float4*)gamma)[c4];
    float4 be  = ((const float4*)beta)[c4];
    float4 v   = ((float4*)out)[idx];
    float4 xr  = ((const float4*)x)[idx];

    float m0 = sm.x * invN, m1 = sm.y * invN, m2 = sm.z * invN, m3 = sm.w * invN;
    float r0 = rsqrtf(sq.x * invN - m0 * m0 + BN_EPS);
    float r1 = rsqrtf(sq.y * invN - m1 * m1 + BN_EPS);
    float r2 = rsqrtf(sq.z * invN - m2 * m2 + BN_EPS);
    float r3 = rsqrtf(sq.w * invN - m3 * m3 + BN_EPS);

    float4 o;
    o.x = fmaxf((v.x - m0) * r0 * g.x + be.x, 0.0f) + xr.x;
    o.y = fmaxf((v.y - m1) * r1 * g.y + be.y, 0.0f) + xr.y;
    o.z = fmaxf((v.z - m2) * r2 * g.z + be.z, 0.0f) + xr.z;
    o.w = fmaxf((v.w - m3) * r3 * g.w + be.w, 0.0f) + xr.w;
    ((float4*)out)[idx] = o;
}

// ---------------------------------------------------------------- launch
extern "C" void kernel_launch(void* const* d_in, const int* in_sizes, int n_in,
                              void* d_out, int out_size, void* d_ws, size_t ws_size,
                              hipStream_t stream) {
    const float* x     = (const float*)d_in[0];
    const int*   ei    = (const int*)d_in[1];    // [2, NE]
    const float* W     = (const float*)d_in[2];
    const float* b     = (const float*)d_in[3];
    const float* gamma = (const float*)d_in[4];
    const float* beta  = (const float*)d_in[5];
    float*       out   = (float*)d_out;

    float* ws    = (float*)d_ws;
    float* h     = ws;                              // NN*DD floats (51.2 MB)
    float* dinv  = h + (size_t)NN * DD;             // NN
    float* sums  = dinv + NN;                       // DD
    float* sumsq = sums + DD;                       // DD
    int*   cnt   = (int*)(sumsq + DD);              // NN
    int*   offs  = cnt + NN;                        // NN
    int*   cur   = offs + NN;                       // NN
    int*   bsum  = cur + NN;                        // 512
    int*   srcs  = bsum + 512;                      // NE

    const int* src = ei;        // edge_index[0]
    const int* dst = ei + NE;   // edge_index[1]

    k_init  <<<(NN + 255) / 256, 256, 0, stream>>>(cnt, sums, sumsq);
    k_count <<<(NE + 255) / 256, 256, 0, stream>>>(dst, cnt);
    k_scan1 <<<NB1, 256, 0, stream>>>(cnt, offs, bsum);
    k_scan2 <<<1, 512, 0, stream>>>(bsum);
    k_scan3 <<<NB1, 256, 0, stream>>>(offs, bsum, cnt, cur, dinv);
    k_fill  <<<(NE + 255) / 256, 256, 0, stream>>>(src, dst, cur, srcs);
    k_gemm  <<<(NN + 31) / 32, 256, 0, stream>>>(x, W, h);
    k_gather<<<(NN + 3) / 4, 256, 0, stream>>>(offs, cnt, srcs, h, dinv, b, out);
    k_stats <<<1024, 256, 0, stream>>>(out, sums, sumsq);
    k_final <<<(NN * DD / 4 + 255) / 256, 256, 0, stream>>>(out, x, gamma, beta, sums, sumsq);
}

// Round 3
// 215.929 us; speedup vs baseline: 3.0397x; 1.2528x over previous
//
#include <hip/hip_runtime.h>

#define NN 100000
#define NE 600000
#define DD 128
#define BN_EPS 1e-5f
#define NB1 391   // (NN+255)/256 scan blocks

typedef __attribute__((ext_vector_type(8))) short bf16x8;
typedef __attribute__((ext_vector_type(4))) float f32x4;

static __device__ __forceinline__ unsigned short f2bf(float f) {
    unsigned u = __float_as_uint(f);
    unsigned r = (u + 0x7FFFu + ((u >> 16) & 1u)) >> 16;   // RNE
    return (unsigned short)r;
}
static __device__ __forceinline__ float bflo(unsigned v) { return __uint_as_float(v << 16); }
static __device__ __forceinline__ float bfhi(unsigned v) { return __uint_as_float(v & 0xFFFF0000u); }

// ---------------------------------------------------------------- init
__global__ __launch_bounds__(256) void k_init(int* __restrict__ cnt,
                                              float* __restrict__ sums,
                                              float* __restrict__ sumsq) {
    int i = blockIdx.x * 256 + threadIdx.x;
    if (i < NN) cnt[i] = 0;
    if (i < DD) { sums[i] = 0.0f; sumsq[i] = 0.0f; }
}

// ---------------------------------------------------------------- count incoming edges
__global__ __launch_bounds__(256) void k_count(const int* __restrict__ dst,
                                               int* __restrict__ cnt) {
    int e = blockIdx.x * 256 + threadIdx.x;
    if (e < NE) atomicAdd(&cnt[dst[e]], 1);
}

// ---------------------------------------------------------------- scan pass 1
__global__ __launch_bounds__(256) void k_scan1(const int* __restrict__ cnt,
                                               int* __restrict__ offs,
                                               int* __restrict__ bsum) {
    __shared__ int tmp[256];
    int tid = threadIdx.x;
    int i = blockIdx.x * 256 + tid;
    int v = (i < NN) ? cnt[i] : 0;
    tmp[tid] = v;
    __syncthreads();
    #pragma unroll
    for (int d = 1; d < 256; d <<= 1) {
        int t = (tid >= d) ? tmp[tid - d] : 0;
        __syncthreads();
        tmp[tid] += t;
        __syncthreads();
    }
    if (i < NN) offs[i] = tmp[tid] - v;
    if (tid == 255) bsum[blockIdx.x] = tmp[255];
}

// ---------------------------------------------------------------- scan pass 2 (1 block)
__global__ __launch_bounds__(512) void k_scan2(int* __restrict__ bsum) {
    __shared__ int tmp[512];
    int tid = threadIdx.x;
    int v = (tid < NB1) ? bsum[tid] : 0;
    tmp[tid] = v;
    __syncthreads();
    #pragma unroll
    for (int d = 1; d < 512; d <<= 1) {
        int t = (tid >= d) ? tmp[tid - d] : 0;
        __syncthreads();
        tmp[tid] += t;
        __syncthreads();
    }
    if (tid < NB1) bsum[tid] = tmp[tid] - v;
}

// ---------------------------------------------------------------- scan pass 3
__global__ __launch_bounds__(256) void k_scan3(int* __restrict__ offs,
                                               const int* __restrict__ bsum,
                                               const int* __restrict__ cnt,
                                               int* __restrict__ cur,
                                               float* __restrict__ dinv) {
    int i = blockIdx.x * 256 + threadIdx.x;
    if (i < NN) {
        int o = offs[i] + bsum[blockIdx.x];
        offs[i] = o;
        cur[i]  = o;
        dinv[i] = rsqrtf((float)(cnt[i] + 1));   // +1 self-loop
    }
}

// ---------------------------------------------------------------- fill CSR with {src, weight} pairs
__global__ __launch_bounds__(256) void k_fill(const int* __restrict__ src,
                                              const int* __restrict__ dst,
                                              const float* __restrict__ dinv,
                                              int* __restrict__ cur,
                                              int2* __restrict__ pairs) {
    int e = blockIdx.x * 256 + threadIdx.x;
    if (e < NE) {
        int s = src[e], t = dst[e];
        int slot = atomicAdd(&cur[t], 1);
        pairs[slot] = make_int2(s, __float_as_int(dinv[s] * dinv[t]));
    }
}

// ---------------------------------------------------------------- W -> Wt (transposed, bf16)
__global__ __launch_bounds__(256) void k_wcvt(const float* __restrict__ W,
                                              unsigned short* __restrict__ Wt) {
    int idx = blockIdx.x * 256 + threadIdx.x;   // 16384
    if (idx < DD * DD) {
        int k = idx >> 7, c = idx & 127;
        Wt[c * DD + k] = f2bf(W[idx]);
    }
}

// ---------------------------------------------------------------- GEMM h = bf16(x) @ bf16(W)  via MFMA
// block = 256 (4 waves), 64 rows/block, 16 rows/wave, W-frags in registers, no LDS
__global__ __launch_bounds__(256) void k_gemm(const float* __restrict__ x,
                                              const unsigned short* __restrict__ Wt, // [c][k] bf16
                                              unsigned short* __restrict__ h) {      // [NN][DD] bf16
    const int tid  = threadIdx.x;
    const int wid  = tid >> 6;
    const int lane = tid & 63;
    const int lm   = lane & 15;   // A-row / B-col within tile
    const int lk   = lane >> 4;   // k-chunk 0..3
    const int rowbase = blockIdx.x * 64 + wid * 16;

    // W fragments: wf[nt][ks] — lane holds Wt[nt*16+lm][ks*32 + lk*8 .. +7]
    bf16x8 wf[8][4];
    #pragma unroll
    for (int nt = 0; nt < 8; ++nt)
        #pragma unroll
        for (int ks = 0; ks < 4; ++ks)
            wf[nt][ks] = *(const bf16x8*)(Wt + (nt * 16 + lm) * DD + ks * 32 + lk * 8);

    int xrow = rowbase + lm;
    if (xrow >= NN) xrow = NN - 1;               // clamp; stores are guarded
    const float* xp = x + (size_t)xrow * DD;

    f32x4 acc[8];
    #pragma unroll
    for (int nt = 0; nt < 8; ++nt) acc[nt] = (f32x4){0.f, 0.f, 0.f, 0.f};

    #pragma unroll
    for (int ks = 0; ks < 4; ++ks) {
        float4 xa = *(const float4*)(xp + ks * 32 + lk * 8);
        float4 xb = *(const float4*)(xp + ks * 32 + lk * 8 + 4);
        bf16x8 a;
        a[0] = (short)f2bf(xa.x); a[1] = (short)f2bf(xa.y);
        a[2] = (short)f2bf(xa.z); a[3] = (short)f2bf(xa.w);
        a[4] = (short)f2bf(xb.x); a[5] = (short)f2bf(xb.y);
        a[6] = (short)f2bf(xb.z); a[7] = (short)f2bf(xb.w);
        #pragma unroll
        for (int nt = 0; nt < 8; ++nt)
            acc[nt] = __builtin_amdgcn_mfma_f32_16x16x32_bf16(a, wf[nt][ks], acc[nt], 0, 0, 0);
    }

    // D layout: row = lk*4 + r, col = nt*16 + lm   [m89-verified]
    #pragma unroll
    for (int nt = 0; nt < 8; ++nt)
        #pragma unroll
        for (int r = 0; r < 4; ++r) {
            int row = rowbase + lk * 4 + r;
            if (row < NN)
                h[(size_t)row * DD + nt * 16 + lm] = f2bf(acc[nt][r]);
        }
}

// ---------------------------------------------------------------- gather: wave/node, shfl-broadcast pairs, 4x ILP
__global__ __launch_bounds__(256) void k_gather(const int* __restrict__ offs,
                                                const int* __restrict__ cnt,
                                                const int2* __restrict__ pairs,
                                                const unsigned short* __restrict__ h, // bf16
                                                const float* __restrict__ dinv,
                                                const float* __restrict__ b,
                                                float* __restrict__ out) {
    int i = blockIdx.x * 4 + (threadIdx.x >> 6);
    if (i >= NN) return;
    int lane = threadIdx.x & 63;
    const unsigned* h2 = (const unsigned*)h;     // 2 bf16 per u32, 64 per row

    float di = dinv[i];
    unsigned sv = h2[(size_t)i * 64 + lane];     // self-loop
    float sn = di * di;
    float2 acc = make_float2(bflo(sv) * sn, bfhi(sv) * sn);

    int beg = offs[i], n = cnt[i];
    for (int base = 0; base < n; base += 64) {
        int m = n - base; if (m > 64) m = 64;
        int2 pr = (lane < m) ? pairs[beg + base + lane] : make_int2(0, 0);
        int k = 0;
        for (; k + 4 <= m; k += 4) {
            int s0 = __shfl(pr.x, k),     s1 = __shfl(pr.x, k + 1);
            int s2 = __shfl(pr.x, k + 2), s3 = __shfl(pr.x, k + 3);
            float w0 = __int_as_float(__shfl(pr.y, k));
            float w1 = __int_as_float(__shfl(pr.y, k + 1));
            float w2 = __int_as_float(__shfl(pr.y, k + 2));
            float w3 = __int_as_float(__shfl(pr.y, k + 3));
            unsigned v0 = h2[(size_t)s0 * 64 + lane];
            unsigned v1 = h2[(size_t)s1 * 64 + lane];
            unsigned v2 = h2[(size_t)s2 * 64 + lane];
            unsigned v3 = h2[(size_t)s3 * 64 + lane];
            acc.x = fmaf(bflo(v0), w0, acc.x); acc.y = fmaf(bfhi(v0), w0, acc.y);
            acc.x = fmaf(bflo(v1), w1, acc.x); acc.y = fmaf(bfhi(v1), w1, acc.y);
            acc.x = fmaf(bflo(v2), w2, acc.x); acc.y = fmaf(bfhi(v2), w2, acc.y);
            acc.x = fmaf(bflo(v3), w3, acc.x); acc.y = fmaf(bfhi(v3), w3, acc.y);
        }
        for (; k < m; ++k) {
            int s = __shfl(pr.x, k);
            float w = __int_as_float(__shfl(pr.y, k));
            unsigned v = h2[(size_t)s * 64 + lane];
            acc.x = fmaf(bflo(v), w, acc.x); acc.y = fmaf(bfhi(v), w, acc.y);
        }
    }
    float2 bb = ((const float2*)b)[lane];
    ((float2*)out)[(size_t)i * 64 + lane] = make_float2(acc.x + bb.x, acc.y + bb.y);
}

// ---------------------------------------------------------------- BN stats
__global__ __launch_bounds__(256) void k_stats(const float* __restrict__ agg,
                                               float* __restrict__ sums,
                                               float* __restrict__ sumsq) {
    __shared__ float s1[256], s2[256];
    int col  = threadIdx.x & 127;
    int half = threadIdx.x >> 7;
    float s = 0.0f, ss = 0.0f;
    for (int r = blockIdx.x * 2 + half; r < NN; r += gridDim.x * 2) {
        float v = agg[(size_t)r * DD + col];
        s += v; ss += v * v;
    }
    s1[threadIdx.x] = s; s2[threadIdx.x] = ss;
    __syncthreads();
    if (half == 0) {
        s  += s1[threadIdx.x + 128];
        ss += s2[threadIdx.x + 128];
        unsafeAtomicAdd(&sums[col],  s);
        unsafeAtomicAdd(&sumsq[col], ss);
    }
}

// ---------------------------------------------------------------- BN apply + ReLU + residual
__global__ __launch_bounds__(256) void k_final(float* __restrict__ out,
                                               const float* __restrict__ x,
                                               const float* __restrict__ gamma,
                                               const float* __restrict__ beta,
                                               const float* __restrict__ sums,
                                               const float* __restrict__ sumsq) {
    int idx = blockIdx.x * 256 + threadIdx.x;
    if (idx >= NN * DD / 4) return;
    int c4 = idx & 31;

    const float invN = 1.0f / (float)NN;
    float4 sm  = ((const float4*)sums)[c4];
    float4 sq  = ((const float4*)sumsq)[c4];
    float4 g   = ((const float4*)gamma)[c4];
    float4 be  = ((const float4*)beta)[c4];
    float4 v   = ((float4*)out)[idx];
    float4 xr  = ((const float4*)x)[idx];

    float m0 = sm.x * invN, m1 = sm.y * invN, m2 = sm.z * invN, m3 = sm.w * invN;
    float r0 = rsqrtf(sq.x * invN - m0 * m0 + BN_EPS);
    float r1 = rsqrtf(sq.y * invN - m1 * m1 + BN_EPS);
    float r2 = rsqrtf(sq.z * invN - m2 * m2 + BN_EPS);
    float r3 = rsqrtf(sq.w * invN - m3 * m3 + BN_EPS);

    float4 o;
    o.x = fmaxf((v.x - m0) * r0 * g.x + be.x, 0.0f) + xr.x;
    o.y = fmaxf((v.y - m1) * r1 * g.y + be.y, 0.0f) + xr.y;
    o.z = fmaxf((v.z - m2) * r2 * g.z + be.z, 0.0f) + xr.z;
    o.w = fmaxf((v.w - m3) * r3 * g.w + be.w, 0.0f) + xr.w;
    ((float4*)out)[idx] = o;
}

// ---------------------------------------------------------------- launch
extern "C" void kernel_launch(void* const* d_in, const int* in_sizes, int n_in,
                              void* d_out, int out_size, void* d_ws, size_t ws_size,
                              hipStream_t stream) {
    const float* x     = (const float*)d_in[0];
    const int*   ei    = (const int*)d_in[1];    // [2, NE]
    const float* W     = (const float*)d_in[2];
    const float* b     = (const float*)d_in[3];
    const float* gamma = (const float*)d_in[4];
    const float* beta  = (const float*)d_in[5];
    float*       out   = (float*)d_out;

    char* base = (char*)d_ws;
    size_t off = 0;
    unsigned short* h = (unsigned short*)(base + off); off += (size_t)NN * DD * 2;  // 25.6 MB
    float* dinv  = (float*)(base + off); off += (size_t)NN * 4;
    float* sums  = (float*)(base + off); off += 512;
    float* sumsq = (float*)(base + off); off += 512;
    int* cnt  = (int*)(base + off); off += (size_t)NN * 4;
    int* offs = (int*)(base + off); off += (size_t)NN * 4;
    int* cur  = (int*)(base + off); off += (size_t)NN * 4;
    int* bsum = (int*)(base + off); off += 2048;
    int2* pairs = (int2*)(base + off); off += (size_t)NE * 8;                        // 4.8 MB
    unsigned short* Wt = (unsigned short*)(base + off); off += DD * DD * 2;

    const int* src = ei;        // edge_index[0]
    const int* dst = ei + NE;   // edge_index[1]

    k_init  <<<(NN + 255) / 256, 256, 0, stream>>>(cnt, sums, sumsq);
    k_count <<<(NE + 255) / 256, 256, 0, stream>>>(dst, cnt);
    k_scan1 <<<NB1, 256, 0, stream>>>(cnt, offs, bsum);
    k_scan2 <<<1, 512, 0, stream>>>(bsum);
    k_scan3 <<<NB1, 256, 0, stream>>>(offs, bsum, cnt, cur, dinv);
    k_fill  <<<(NE + 255) / 256, 256, 0, stream>>>(src, dst, dinv, cur, pairs);
    k_wcvt  <<<64, 256, 0, stream>>>(W, Wt);
    k_gemm  <<<(NN + 63) / 64, 256, 0, stream>>>(x, Wt, h);
    k_gather<<<(NN + 3) / 4, 256, 0, stream>>>(offs, cnt, pairs, h, dinv, b, out);
    k_stats <<<1024, 256, 0, stream>>>(out, sums, sumsq);
    k_final <<<(NN * DD / 4 + 255) / 256, 256, 0, stream>>>(out, x, gamma, beta, sums, sumsq);
}

// Round 5
// 175.042 us; speedup vs baseline: 3.7497x; 1.2336x over previous
//
#include <hip/hip_runtime.h>

#define NN 100000
#define NE 600000
#define DD 128
#define BN_EPS 1e-5f
#define NB1 391    // (NN+255)/256 scan blocks
#define NBG 4096   // gather blocks

typedef __attribute__((ext_vector_type(8))) short bf16x8;
typedef __attribute__((ext_vector_type(4))) float f32x4;

static __device__ __forceinline__ unsigned short f2bf(float f) {
    unsigned u = __float_as_uint(f);
    unsigned r = (u + 0x7FFFu + ((u >> 16) & 1u)) >> 16;   // RNE
    return (unsigned short)r;
}
static __device__ __forceinline__ float bflo(unsigned v) { return __uint_as_float(v << 16); }
static __device__ __forceinline__ float bfhi(unsigned v) { return __uint_as_float(v & 0xFFFF0000u); }

// ---------------------------------------------------------------- init: cnt=0, stats=0, W->Wt bf16 transpose
__global__ __launch_bounds__(256) void k_init(int* __restrict__ cnt,
                                              float* __restrict__ stats,
                                              const float* __restrict__ W,
                                              unsigned short* __restrict__ Wt) {
    int i = blockIdx.x * 256 + threadIdx.x;
    if (i < NN) cnt[i] = 0;
    if (i < 256) stats[i] = 0.0f;
    if (i < DD * DD) {
        int k = i >> 7, c = i & 127;
        Wt[c * DD + k] = f2bf(W[i]);
    }
}

// ---------------------------------------------------------------- count incoming edges
__global__ __launch_bounds__(256) void k_count(const int* __restrict__ dst,
                                               int* __restrict__ cnt) {
    int e = blockIdx.x * 256 + threadIdx.x;
    if (e < NE) atomicAdd(&cnt[dst[e]], 1);
}

// ---------------------------------------------------------------- scan pass 1 over (cnt[i]+1)  [self edge included]
__global__ __launch_bounds__(256) void k_scan1(const int* __restrict__ cnt,
                                               int* __restrict__ offs,
                                               int* __restrict__ bsum) {
    __shared__ int tmp[256];
    int tid = threadIdx.x;
    int i = blockIdx.x * 256 + tid;
    int v = (i < NN) ? (cnt[i] + 1) : 0;
    tmp[tid] = v;
    __syncthreads();
    #pragma unroll
    for (int d = 1; d < 256; d <<= 1) {
        int t = (tid >= d) ? tmp[tid - d] : 0;
        __syncthreads();
        tmp[tid] += t;
        __syncthreads();
    }
    if (i < NN) offs[i] = tmp[tid] - v;
    if (tid == 255) bsum[blockIdx.x] = tmp[255];
}

// ---------------------------------------------------------------- scan pass 2 (1 block)
__global__ __launch_bounds__(512) void k_scan2(int* __restrict__ bsum) {
    __shared__ int tmp[512];
    int tid = threadIdx.x;
    int v = (tid < NB1) ? bsum[tid] : 0;
    tmp[tid] = v;
    __syncthreads();
    #pragma unroll
    for (int d = 1; d < 512; d <<= 1) {
        int t = (tid >= d) ? tmp[tid - d] : 0;
        __syncthreads();
        tmp[tid] += t;
        __syncthreads();
    }
    if (tid < NB1) bsum[tid] = tmp[tid] - v;
}

// ---------------------------------------------------------------- scan pass 3: finalize offs, self edge, cursor, dinv
__global__ __launch_bounds__(256) void k_scan3(int* __restrict__ offs,
                                               const int* __restrict__ bsum,
                                               const int* __restrict__ cnt,
                                               int* __restrict__ cur,
                                               float* __restrict__ dinv,
                                               int2* __restrict__ pairs) {
    int i = blockIdx.x * 256 + threadIdx.x;
    if (i < NN) {
        int o = offs[i] + bsum[blockIdx.x];
        offs[i] = o;
        float di = rsqrtf((float)(cnt[i] + 1));
        dinv[i] = di;
        pairs[o] = make_int2(i, __float_as_int(di * di));  // self edge at slot 0
        cur[i]  = o + 1;
        if (i == 0) offs[NN] = NE + NN;                    // sentinel
    }
}

// ---------------------------------------------------------------- fill CSR with {src, weight} pairs
__global__ __launch_bounds__(256) void k_fill(const int* __restrict__ src,
                                              const int* __restrict__ dst,
                                              const float* __restrict__ dinv,
                                              int* __restrict__ cur,
                                              int2* __restrict__ pairs) {
    int e = blockIdx.x * 256 + threadIdx.x;
    if (e < NE) {
        int s = src[e], t = dst[e];
        int slot = atomicAdd(&cur[t], 1);
        pairs[slot] = make_int2(s, __float_as_int(dinv[s] * dinv[t]));
    }
}

// ---------------------------------------------------------------- GEMM h = bf16(x) @ bf16(W)  via MFMA
__global__ __launch_bounds__(256) void k_gemm(const float* __restrict__ x,
                                              const unsigned short* __restrict__ Wt, // [c][k] bf16
                                              unsigned short* __restrict__ h) {      // [NN][DD] bf16
    const int tid  = threadIdx.x;
    const int wid  = tid >> 6;
    const int lane = tid & 63;
    const int lm   = lane & 15;
    const int lk   = lane >> 4;
    const int rowbase = blockIdx.x * 64 + wid * 16;

    bf16x8 wf[8][4];
    #pragma unroll
    for (int nt = 0; nt < 8; ++nt)
        #pragma unroll
        for (int ks = 0; ks < 4; ++ks)
            wf[nt][ks] = *(const bf16x8*)(Wt + (nt * 16 + lm) * DD + ks * 32 + lk * 8);

    int xrow = rowbase + lm;
    if (xrow >= NN) xrow = NN - 1;
    const float* xp = x + (size_t)xrow * DD;

    f32x4 acc[8];
    #pragma unroll
    for (int nt = 0; nt < 8; ++nt) acc[nt] = (f32x4){0.f, 0.f, 0.f, 0.f};

    #pragma unroll
    for (int ks = 0; ks < 4; ++ks) {
        float4 xa = *(const float4*)(xp + ks * 32 + lk * 8);
        float4 xb = *(const float4*)(xp + ks * 32 + lk * 8 + 4);
        bf16x8 a;
        a[0] = (short)f2bf(xa.x); a[1] = (short)f2bf(xa.y);
        a[2] = (short)f2bf(xa.z); a[3] = (short)f2bf(xa.w);
        a[4] = (short)f2bf(xb.x); a[5] = (short)f2bf(xb.y);
        a[6] = (short)f2bf(xb.z); a[7] = (short)f2bf(xb.w);
        #pragma unroll
        for (int nt = 0; nt < 8; ++nt)
            acc[nt] = __builtin_amdgcn_mfma_f32_16x16x32_bf16(a, wf[nt][ks], acc[nt], 0, 0, 0);
    }

    #pragma unroll
    for (int nt = 0; nt < 8; ++nt)
        #pragma unroll
        for (int r = 0; r < 4; ++r) {
            int row = rowbase + lk * 4 + r;
            if (row < NN)
                h[(size_t)row * DD + nt * 16 + lm] = f2bf(acc[nt][r]);
        }
}

// ---------------------------------------------------------------- gather: 16 lanes/row, 4 edges in flight, fused stats
__global__ __launch_bounds__(256) void k_gather(const int* __restrict__ offs,
                                                const int2* __restrict__ pairs,
                                                const unsigned short* __restrict__ h, // bf16
                                                const float* __restrict__ b,
                                                float* __restrict__ out,
                                                float* __restrict__ partial) {
    const int tid  = threadIdx.x;
    const int wid  = tid >> 6;
    const int lane = tid & 63;
    const int g    = lane >> 4;    // edge group 0..3
    const int sl   = lane & 15;    // row-slice: cols sl*8..sl*8+7
    const uint4* h4 = (const uint4*)h;     // 16B = 8 bf16 per uint4

    float4 b0 = ((const float4*)b)[sl * 2];
    float4 b1 = ((const float4*)b)[sl * 2 + 1];

    float s_[8], ss_[8];
    #pragma unroll
    for (int j = 0; j < 8; ++j) { s_[j] = 0.0f; ss_[j] = 0.0f; }

    for (int i = blockIdx.x * 4 + wid; i < NN; i += NBG * 4) {
        int beg = offs[i];
        int n   = offs[i + 1] - beg;

        float acc[8];
        #pragma unroll
        for (int j = 0; j < 8; ++j) acc[j] = 0.0f;

        for (int base = 0; base < n; base += 64) {
            int m = n - base; if (m > 64) m = 64;
            int2 pr = (lane < m) ? pairs[beg + base + lane] : make_int2(0, 0);
            int iters = (m + 3) >> 2;
            for (int it = 0; it < iters; ++it) {
                int k = it * 4 + g;
                // shfl OUTSIDE any divergent branch: all 64 lanes execute, so
                // every source lane contributes (lanes >= m hold defined (0,0)).
                int   srow = __shfl(pr.x, k);
                float w    = __int_as_float(__shfl(pr.y, k));
                if (k < m) {
                    uint4 v = h4[(size_t)srow * 16 + sl];
                    acc[0] = fmaf(bflo(v.x), w, acc[0]);
                    acc[1] = fmaf(bfhi(v.x), w, acc[1]);
                    acc[2] = fmaf(bflo(v.y), w, acc[2]);
                    acc[3] = fmaf(bfhi(v.y), w, acc[3]);
                    acc[4] = fmaf(bflo(v.z), w, acc[4]);
                    acc[5] = fmaf(bfhi(v.z), w, acc[5]);
                    acc[6] = fmaf(bflo(v.w), w, acc[6]);
                    acc[7] = fmaf(bfhi(v.w), w, acc[7]);
                }
            }
        }
        // combine the 4 edge groups (all lanes end with full value, 4x duplicated)
        #pragma unroll
        for (int j = 0; j < 8; ++j) {
            acc[j] += __shfl_xor(acc[j], 16);
            acc[j] += __shfl_xor(acc[j], 32);
        }
        float o[8];
        o[0] = acc[0] + b0.x; o[1] = acc[1] + b0.y;
        o[2] = acc[2] + b0.z; o[3] = acc[3] + b0.w;
        o[4] = acc[4] + b1.x; o[5] = acc[5] + b1.y;
        o[6] = acc[6] + b1.z; o[7] = acc[7] + b1.w;
        if (g == 0) {
            ((float4*)out)[(size_t)i * 32 + sl * 2]     = make_float4(o[0], o[1], o[2], o[3]);
            ((float4*)out)[(size_t)i * 32 + sl * 2 + 1] = make_float4(o[4], o[5], o[6], o[7]);
        }
        #pragma unroll
        for (int j = 0; j < 8; ++j) { s_[j] += o[j]; ss_[j] += o[j] * o[j]; }
    }

    // block-level stats reduce (group-0 lanes hold valid s_/ss_; others are duplicates)
    __shared__ float lsum[4][128], lss[4][128];
    if (g == 0) {
        #pragma unroll
        for (int j = 0; j < 8; ++j) { lsum[wid][sl * 8 + j] = s_[j]; lss[wid][sl * 8 + j] = ss_[j]; }
    }
    __syncthreads();
    if (tid < 128) {
        float a = lsum[0][tid] + lsum[1][tid] + lsum[2][tid] + lsum[3][tid];
        float c = lss[0][tid]  + lss[1][tid]  + lss[2][tid]  + lss[3][tid];
        partial[blockIdx.x * 256 + tid]       = a;
        partial[blockIdx.x * 256 + 128 + tid] = c;
    }
}

// ---------------------------------------------------------------- reduce partials -> stats[256] (sums | sumsq)
__global__ __launch_bounds__(256) void k_red(const float* __restrict__ partial,
                                             float* __restrict__ stats) {
    int tid = threadIdx.x;
    float a = 0.0f;
    int rbeg = blockIdx.x * (NBG / 64);
    for (int r = 0; r < NBG / 64; ++r)
        a += partial[(size_t)(rbeg + r) * 256 + tid];
    unsafeAtomicAdd(&stats[tid], a);
}

// ---------------------------------------------------------------- BN apply + ReLU + residual
__global__ __launch_bounds__(256) void k_final(float* __restrict__ out,
                                               const float* __restrict__ x,
                                               const float* __restrict__ gamma,
                                               const float* __restrict__ beta,
                                               const float* __restrict__ stats) {
    int idx = blockIdx.x * 256 + threadIdx.x;
    if (idx >= NN * DD / 4) return;
    int c4 = idx & 31;

    const float invN = 1.0f / (float)NN;
    float4 sm  = ((const float4*)stats)[c4];
    float4 sq  = ((const float4*)stats)[32 + c4];
    float4 g   = ((const float4*)gamma)[c4];
    float4 be  = ((const float4*)beta)[c4];
    float4 v   = ((float4*)out)[idx];
    float4 xr  = ((const float4*)x)[idx];

    float m0 = sm.x * invN, m1 = sm.y * invN, m2 = sm.z * invN, m3 = sm.w * invN;
    float r0 = rsqrtf(sq.x * invN - m0 * m0 + BN_EPS);
    float r1 = rsqrtf(sq.y * invN - m1 * m1 + BN_EPS);
    float r2 = rsqrtf(sq.z * invN - m2 * m2 + BN_EPS);
    float r3 = rsqrtf(sq.w * invN - m3 * m3 + BN_EPS);

    float4 o;
    o.x = fmaxf((v.x - m0) * r0 * g.x + be.x, 0.0f) + xr.x;
    o.y = fmaxf((v.y - m1) * r1 * g.y + be.y, 0.0f) + xr.y;
    o.z = fmaxf((v.z - m2) * r2 * g.z + be.z, 0.0f) + xr.z;
    o.w = fmaxf((v.w - m3) * r3 * g.w + be.w, 0.0f) + xr.w;
    ((float4*)out)[idx] = o;
}

// ---------------------------------------------------------------- launch
extern "C" void kernel_launch(void* const* d_in, const int* in_sizes, int n_in,
                              void* d_out, int out_size, void* d_ws, size_t ws_size,
                              hipStream_t stream) {
    const float* x     = (const float*)d_in[0];
    const int*   ei    = (const int*)d_in[1];    // [2, NE]
    const float* W     = (const float*)d_in[2];
    const float* b     = (const float*)d_in[3];
    const float* gamma = (const float*)d_in[4];
    const float* beta  = (const float*)d_in[5];
    float*       out   = (float*)d_out;

    // 256B-aligned workspace carve (int2/bf16x8 loads require natural alignment)
    char*  base = (char*)d_ws;
    size_t off  = 0;
    auto carve = [&](size_t bytes) -> void* {
        void* p = base + off;
        off = (off + bytes + 255) & ~(size_t)255;
        return p;
    };
    unsigned short* h     = (unsigned short*)carve((size_t)NN * DD * 2);   // 25.6 MB
    float*          dinv  = (float*)carve((size_t)NN * 4);
    float*          stats = (float*)carve(256 * 4);
    int*            cnt   = (int*)carve((size_t)NN * 4);
    int*            offs  = (int*)carve((size_t)(NN + 1) * 4);
    int*            cur   = (int*)carve((size_t)NN * 4);
    int*            bsum  = (int*)carve(2048);
    int2*           pairs = (int2*)carve((size_t)(NE + NN) * 8);           // 5.6 MB
    unsigned short* Wt    = (unsigned short*)carve(DD * DD * 2);
    float*          partial = (float*)carve((size_t)NBG * 256 * 4);        // 4 MB

    const int* src = ei;        // edge_index[0]
    const int* dst = ei + NE;   // edge_index[1]

    k_init  <<<NB1, 256, 0, stream>>>(cnt, stats, W, Wt);
    k_count <<<(NE + 255) / 256, 256, 0, stream>>>(dst, cnt);
    k_scan1 <<<NB1, 256, 0, stream>>>(cnt, offs, bsum);
    k_scan2 <<<1, 512, 0, stream>>>(bsum);
    k_scan3 <<<NB1, 256, 0, stream>>>(offs, bsum, cnt, cur, dinv, pairs);
    k_fill  <<<(NE + 255) / 256, 256, 0, stream>>>(src, dst, dinv, cur, pairs);
    k_gemm  <<<(NN + 63) / 64, 256, 0, stream>>>(x, Wt, h);
    k_gather<<<NBG, 256, 0, stream>>>(offs, pairs, h, b, out, partial);
    k_red   <<<64, 256, 0, stream>>>(partial, stats);
    k_final <<<(NN * DD / 4 + 255) / 256, 256, 0, stream>>>(out, x, gamma, beta, stats);
}